// Round 6
// baseline (726.652 us; speedup 1.0000x reference)
//
#include <hip/hip_runtime.h>
#include <math.h>

// ---------------------------------------------------------------------------
// GPT transformer block, internal bf16 compute / fp32 accumulate.
// B=4, T=2048, D=1024 (8192 rows), 3D=3072, 4D=4096.
// Round 12: B-operand moved out of LDS. B fragments load directly
// global->reg (global_load_dwordx4, L2-resident weights), double-buffered in
// the SAME 32 VGPRs via role swap (jp1 buffer frees at ph6 -> holds next
// tile's jp0; jp0 frees at ph7 -> reloaded at boundary). Static counted
// vmcnt: ph0(8), ph1(4), boundary(4) [BM=128: 6/2/4], tail-guarded.
// DS reads/wave/tile 24 -> 16, LDS writes halve, LDS 64/32 KiB, B latency
// decoupled from barriers. A path (stage/swizzle/ds_read/lgkm) = r11 proven.
// Occupancy is register-capped at 8 waves/CU (248 regs) -- all overlap must
// come from 2 waves/SIMD, so shrinking the serialized LDS stream is the lever.
// ---------------------------------------------------------------------------

typedef unsigned short u16;
typedef __attribute__((ext_vector_type(8))) short bf16x8;   // 8 bf16 = 4 VGPRs
typedef __attribute__((ext_vector_type(8))) unsigned short u16x8;
typedef __attribute__((ext_vector_type(4))) float f32x4;

#define DEV __device__ __forceinline__

#define GLOAD_LDS16(gp, lp)                                                     \
    __builtin_amdgcn_global_load_lds(                                           \
        (const __attribute__((address_space(1))) void*)(gp),                    \
        (__attribute__((address_space(3))) void*)(lp), 16, 0, 0)

// inline-asm LDS b128 read: invisible to SIInsertWaitcnts; pair with explicit
// counted s_waitcnt lgkmcnt + sched_barrier(0) before use (rule #18).
#define DSR128(dst_, p_)                                                        \
    asm volatile("ds_read_b128 %0, %1"                                          \
                 : "=v"(dst_)                                                   \
                 : "v"((unsigned)(unsigned long long)                           \
                       (__attribute__((address_space(3))) const void*)(p_)))

// inline-asm global 16B load to 4 VGPRs (manual vmcnt discipline).
#define GLDX4(dst_, p_)                                                         \
    asm volatile("global_load_dwordx4 %0, %1, off"                              \
                 : "=v"(dst_) : "v"(p_))

DEV float bf2f(u16 h) {
    union { unsigned u; float f; } t; t.u = ((unsigned)h) << 16; return t.f;
}
DEV u16 f2bf(float f) {
    union { unsigned u; float f; } t; t.f = f;
    unsigned u = t.u;
    return (u16)((u + 0x7FFFu + ((u >> 16) & 1u)) >> 16);   // round-nearest-even
}
DEV float loadIn(const void* p, long i, int isbf) {
    return isbf ? bf2f(((const u16*)p)[i]) : ((const float*)p)[i];
}
// gelu(x) = 0.5x(1+tanh(u)) = x * sigmoid(2u)
DEV float gelu_fast(float x) {
    float u = 1.5957691216057308f * (x + 0.044715f * x * x * x);  // 2*sqrt(2/pi)
    return x * __builtin_amdgcn_rcpf(1.0f + __expf(-u));
}

DEV float waveSum(float v) {
    #pragma unroll
    for (int o = 32; o > 0; o >>= 1) v += __shfl_down(v, o, 64);
    return v;
}
DEV float waveMax(float v) {
    #pragma unroll
    for (int o = 32; o > 0; o >>= 1) v = fmaxf(v, __shfl_down(v, o, 64));
    return v;
}

template <bool IS_MAX>
DEV float blockReduce(float v) {
    __shared__ float tmp[5];
    __syncthreads();
    v = IS_MAX ? waveMax(v) : waveSum(v);
    int lane = threadIdx.x & 63, w = threadIdx.x >> 6;
    if (lane == 0) tmp[w] = v;
    __syncthreads();
    if (threadIdx.x == 0) {
        float r = tmp[0];
        for (int i = 1; i < 4; i++) r = IS_MAX ? fmaxf(r, tmp[i]) : (r + tmp[i]);
        tmp[4] = r;
    }
    __syncthreads();
    return tmp[4];
}

// ---------------- dtype detection (1 block) --------------------------------
__global__ void detect_dtype(const u16* __restrict__ xr, int* __restrict__ flag) {
    const int tid = threadIdx.x;           // 256
    int cnt = 0;
    #pragma unroll
    for (int i = 0; i < 16; i++) {
        unsigned u = xr[2 * (tid + 256 * i)];      // even u16 indices
        unsigned e = (u >> 7) & 0xFF;              // bf16 exponent field
        cnt += (e >= 100 && e <= 140) ? 1 : 0;     // ~always for bf16 N(0,1)
    }
    __shared__ int sh[4];
    #pragma unroll
    for (int o = 32; o > 0; o >>= 1) cnt += __shfl_down(cnt, o, 64);
    if ((tid & 63) == 0) sh[tid >> 6] = cnt;
    __syncthreads();
    if (tid == 0) flag[0] = (sh[0] + sh[1] + sh[2] + sh[3] > 2048) ? 1 : 0;
}

// ---------------- LayerNorm (D=1024, one 256-thread block per row) ---------
template <bool RAW_IN>
__global__ void ln_kernel(const void* __restrict__ x, const void* __restrict__ g,
                          const void* __restrict__ b, u16* __restrict__ out,
                          const int* __restrict__ flagp) {
    const int isbf = *flagp;
    const int inbf = RAW_IN ? isbf : 1;
    const long base = (long)blockIdx.x * 1024;
    const int tid = threadIdx.x;
    float v[4];
    #pragma unroll
    for (int j = 0; j < 4; j++) v[j] = loadIn(x, base + tid + 256 * j, inbf);
    float mu = blockReduce<false>(v[0] + v[1] + v[2] + v[3]) * (1.0f / 1024.0f);
    float d[4], sq = 0.f;
    #pragma unroll
    for (int j = 0; j < 4; j++) { d[j] = v[j] - mu; sq += d[j] * d[j]; }
    float var = blockReduce<false>(sq) * (1.0f / 1024.0f);
    float rstd = rsqrtf(var + 1e-5f);
    #pragma unroll
    for (int j = 0; j < 4; j++) {
        int c = tid + 256 * j;
        out[base + c] = f2bf(d[j] * rstd * loadIn(g, c, isbf) + loadIn(b, c, isbf));
    }
}

// ---------------- 32x32 transpose -> bf16 ----------------------------------
__global__ void transpose_to_bf16(const void* __restrict__ in, int ldin, long inBatch,
                                  u16* __restrict__ out, int ldout, long outBatch,
                                  const int* __restrict__ flagp) {
    __shared__ u16 tile[32][33];
    const int isbf = flagp ? *flagp : 1;
    const long ibase = (long)blockIdx.z * inBatch;
    out += (long)blockIdx.z * outBatch;
    const int bc = blockIdx.x * 32, br = blockIdx.y * 32;
    const int tx = threadIdx.x & 31, ty = threadIdx.x >> 5;   // 256 thr
    #pragma unroll
    for (int i = 0; i < 32; i += 8)
        tile[ty + i][tx] = f2bf(loadIn(in, ibase + (long)(br + ty + i) * ldin + bc + tx, isbf));
    __syncthreads();
    #pragma unroll
    for (int i = 0; i < 32; i += 8)
        out[(long)(bc + ty + i) * ldout + br + tx] = tile[tx][ty + i];
}

// ---------------- BMx256 GEMM, A in LDS, B global->reg ---------------------
// C[M,N] = A[M,K] @ (Bt[N,K])^T (+epilogue). M%BM==0, N%256==0, K%64==0.
// 512 threads = 8 waves (2M x 4N), per-wave C tile (BM/2)x64.
// LDS: 2 K-tile slots x A BMx64 bf16 (64 / 32 KiB). A granule-swizzled
// (g ^ (r&7)), staged via global_load_lds with pre-swizzled source col.
// B: per-wave-private rows, loaded global->reg (L2-hot), role-swap dbuf.
// Per K-tile (BM=256): snake phases (mq,jp) (0,0)(0,1)(1,1)(1,0)(2,0)(2,1)
// (3,1)(3,0); A-quad ds_reads 2 phases ahead under counted lgkm; B-next jp0
// issued after ph6 into the freed jp1 buffer, B-next jp1 at boundary.
// vmcnt: ph0(8), ph1(4), boundary(4) -- loads stay in flight across barriers.
// MODE: 0 qkv +bias->bf16   1 scores *scale->bf16   2 pv plain->bf16
//       3 proj +bias+res(raw)->bf16   4 fc +bias,gelu->bf16
//       5 fc2 +bias+res(bf16)->flag dtype
// CAUSAL: 0 none (T1 XCD swizzle), 1 triangular tile enum (BM=256 only),
//         2 K clamp to m0+BM (pv)
template <int MODE, int CAUSAL, int BM>
__global__ __launch_bounds__(512, 2) void gemm_8ph(
        const u16* __restrict__ A, int lda, long aBatch,
        const u16* __restrict__ Bt, int ldb, long bBatch,
        const void* __restrict__ bias,
        void* __restrict__ Cv, int ldc, long cBatch,
        const void* __restrict__ res,
        float scale, const int* __restrict__ flagp, int K) {
    constexpr int AQ = BM / 64;                     // A stage instrs / thread
    constexpr int MI = BM / 32;                     // acc M frags per wave
    __shared__ __align__(16) u16 sA[2][BM * 64];

    int m0, n0;
    if (CAUSAL == 1) {
        // enumerate lower-triangular 256^2 tiles: bx -> (ti, tj), tj <= ti
        const int bx = blockIdx.x;
        int ti = (int)((sqrtf(8.0f * bx + 1.0f) - 1.0f) * 0.5f);
        while ((ti + 1) * (ti + 2) / 2 <= bx) ++ti;
        while (ti * (ti + 1) / 2 > bx) --ti;
        m0 = ti * 256;
        n0 = (bx - ti * (ti + 1) / 2) * 256;
    } else if (CAUSAL == 2) {
        m0 = (gridDim.y - 1 - blockIdx.y) * BM;    // big-NT blocks dispatch first
        n0 = blockIdx.x * 256;
    } else {
        // T1: bijective XCD chunk swizzle (launches have nwg % 8 == 0)
        const int gx  = gridDim.x;
        const int nwg = gx * gridDim.y;
        const int fid = blockIdx.y * gx + blockIdx.x;
        const int swz = (fid & 7) * (nwg >> 3) + (fid >> 3);
        m0 = (swz / gx) * BM;
        n0 = (swz % gx) * 256;
    }
    const int bz = blockIdx.z;
    A  += (long)bz * aBatch;
    Bt += (long)bz * bBatch;

    const int tid  = threadIdx.x;
    const int lane = tid & 63, wv = tid >> 6;
    const int wm = wv >> 2, wn = wv & 3;            // 2 x 4 wave grid
    const int l16 = lane & 15, quad = lane >> 4;
    const int xg = l16 & 7;                         // A read-side granule XOR

    // A staging mapping: 512 threads, linear LDS dest, pre-swizzled source
    const int rq   = tid >> 3;                      // 0..63
    const int gsrc = ((tid & 7) ^ (rq & 7)) * 8;    // pre-swizzled source col
    const int gdst = (tid & 7) * 8;                 // linear dest granule
    const int rAb  = (rq < 32) ? rq : 96 + rq;      // A rows (BM=256 chunking)

    // B per-lane base: row (n0 + wn*64 + l16), col chunk quad*8
    const u16* bbase = Bt + (long)(n0 + wn * 64 + l16) * ldb + quad * 8;
    const long bj = (long)16 * ldb;                 // +16 rows

    int NT = K >> 6;
    if (CAUSAL == 2) NT = min(K, m0 + BM) >> 6;     // probs zero past t|255

#define STAGE_A(t_, q_) do {                                                     \
        const int sl_ = (t_) & 1;                                               \
        const int k0_ = (t_) << 6;                                              \
        const int ra_ = (BM == 256) ? (((q_) << 5) + rAb) : (((q_) << 6) + rq); \
        GLOAD_LDS16(A + (long)(m0 + ra_) * lda + k0_ + gsrc,                    \
                    &sA[sl_][ra_ * 64 + gdst]);                                 \
    } while (0)

#define STAGE_ALL(t_) do {                                                       \
        _Pragma("unroll")                                                       \
        for (int q_ = 0; q_ < AQ; ++q_) STAGE_A(t_, q_);                        \
    } while (0)

#define BAR8() asm volatile("s_barrier" ::: "memory")

#define WVMC(n_) do {                                                            \
        asm volatile("s_waitcnt vmcnt(" #n_ ")" ::: "memory");                   \
        __builtin_amdgcn_sched_barrier(0); } while (0)

#define WLGKM(n_) do {                                                           \
        asm volatile("s_waitcnt lgkmcnt(" #n_ ")" ::: "memory");                 \
        __builtin_amdgcn_sched_barrier(0); } while (0)

    // A quadrant reads for quad qn_ (4x b128) into buf_[2][2]
#define RD_A4(buf_, qn_, sl_) do {                                               \
        DSR128(buf_[0][0], &sA[sl_][(wm * (BM / 2) + (2 * (qn_) + 0) * 16 + l16) * 64 \
                                    + (((0 * 4 + quad) ^ xg) * 8)]);             \
        DSR128(buf_[0][1], &sA[sl_][(wm * (BM / 2) + (2 * (qn_) + 0) * 16 + l16) * 64 \
                                    + (((1 * 4 + quad) ^ xg) * 8)]);             \
        DSR128(buf_[1][0], &sA[sl_][(wm * (BM / 2) + (2 * (qn_) + 1) * 16 + l16) * 64 \
                                    + (((0 * 4 + quad) ^ xg) * 8)]);             \
        DSR128(buf_[1][1], &sA[sl_][(wm * (BM / 2) + (2 * (qn_) + 1) * 16 + l16) * 64 \
                                    + (((1 * 4 + quad) ^ xg) * 8)]);             \
    } while (0)

    // B half jp_ of tile t_: 4x global dwordx4 into buf_[2][2]
#define LD_B4(buf_, jp_, t_) do {                                                \
        const u16* p_ = bbase + (long)(2 * (jp_)) * bj + ((t_) << 6);            \
        GLDX4(buf_[0][0], p_);                                                   \
        GLDX4(buf_[0][1], p_ + 32);                                              \
        GLDX4(buf_[1][0], p_ + bj);                                              \
        GLDX4(buf_[1][1], p_ + bj + 32);                                         \
    } while (0)

    // 8 MFMA: acc[2*mq_+f][2*jp_+jj] += A_[f][s] * B_[jj][s]
#define MFMA8(mq_, jp_, A_, B_) do {                                             \
        __builtin_amdgcn_s_setprio(1);                                          \
        _Pragma("unroll")                                                        \
        for (int f_ = 0; f_ < 2; ++f_)                                           \
            _Pragma("unroll")                                                    \
            for (int jj_ = 0; jj_ < 2; ++jj_)                                    \
                acc[2 * (mq_) + f_][2 * (jp_) + jj_] =                           \
                    __builtin_amdgcn_mfma_f32_16x16x32_bf16(                     \
                        A_[f_][0], B_[jj_][0],                                   \
                        acc[2 * (mq_) + f_][2 * (jp_) + jj_], 0, 0, 0);          \
        _Pragma("unroll")                                                        \
        for (int f_ = 0; f_ < 2; ++f_)                                           \
            _Pragma("unroll")                                                    \
            for (int jj_ = 0; jj_ < 2; ++jj_)                                    \
                acc[2 * (mq_) + f_][2 * (jp_) + jj_] =                           \
                    __builtin_amdgcn_mfma_f32_16x16x32_bf16(                     \
                        A_[f_][1], B_[jj_][1],                                   \
                        acc[2 * (mq_) + f_][2 * (jp_) + jj_], 0, 0, 0);          \
        __builtin_amdgcn_s_setprio(0);                                          \
    } while (0)

    f32x4 acc[MI][4];
    #pragma unroll
    for (int i = 0; i < MI; i++)
        #pragma unroll
        for (int j = 0; j < 4; j++) acc[i][j] = f32x4{0.f, 0.f, 0.f, 0.f};

    bf16x8 afA[2][2], afB[2][2], R0[2][2], R1[2][2];

    // prologue: B(0) both halves (R0=jp0, R1=jp1) + stage A(0); drain; bar.
    LD_B4(R0, 0, 0);
    LD_B4(R1, 1, 0);
    STAGE_ALL(0);
    WVMC(0);
    BAR8();
    RD_A4(afA, 0, 0);

    // tile body: BP_ holds jp0, BQ_ holds jp1 for this tile. After jp1's last
    // use, BQ_ is reloaded with tile u+1's jp0; BP_ reloaded at the boundary
    // with tile u+1's jp1. Roles swap each tile -> call alternately.
#define TILE256(u_, BP_, BQ_) do {                                               \
        const int su_ = (u_) & 1, sn_ = su_ ^ 1;                                 \
        if ((u_) + 1 < NT) STAGE_ALL((u_) + 1);                                  \
        /* ph0 (0,jp0) */                                                        \
        RD_A4(afB, 1, su_);                                                      \
        if ((u_) + 1 < NT) { WVMC(8); } else { WVMC(4); }                        \
        WLGKM(4); MFMA8(0, 0, afA, BP_);                                         \
        /* ph1 (0,jp1) */                                                        \
        if ((u_) + 1 < NT) { WVMC(4); } else { WVMC(0); }                        \
        MFMA8(0, 1, afA, BQ_);                                                   \
        /* ph2 (1,jp1) */                                                        \
        RD_A4(afA, 2, su_);                                                      \
        WLGKM(4); MFMA8(1, 1, afB, BQ_);                                         \
        /* ph3 (1,jp0) */                                                        \
        MFMA8(1, 0, afB, BP_);                                                   \
        /* ph4 (2,jp0) */                                                        \
        RD_A4(afB, 3, su_);                                                      \
        WLGKM(4); MFMA8(2, 0, afA, BP_);                                         \
        /* ph5 (2,jp1) */                                                        \
        MFMA8(2, 1, afA, BQ_);                                                   \
        /* ph6 (3,jp1) -- jp1 last use; then fetch next jp0 into BQ_ */          \
        WLGKM(0); MFMA8(3, 1, afB, BQ_);                                         \
        if ((u_) + 1 < NT) LD_B4(BQ_, 0, (u_) + 1);                              \
        /* ph7 (3,jp0) -- jp0 last use */                                        \
        MFMA8(3, 0, afB, BP_);                                                   \
        /* boundary */                                                           \
        BAR8();                                                                  \
        if ((u_) + 1 < NT) { WVMC(4); } else { WVMC(0); }                        \
        BAR8();                                                                  \
        if ((u_) + 1 < NT) {                                                     \
            LD_B4(BP_, 1, (u_) + 1);                                             \
            RD_A4(afA, 0, sn_);                                                  \
        }                                                                        \
    } while (0)

#define TILE128(u_, BP_, BQ_) do {                                               \
        const int su_ = (u_) & 1, sn_ = su_ ^ 1;                                 \
        if ((u_) + 1 < NT) STAGE_ALL((u_) + 1);                                  \
        /* ph0 (0,jp0) */                                                        \
        RD_A4(afB, 1, su_);                                                      \
        if ((u_) + 1 < NT) { WVMC(6); } else { WVMC(4); }                        \
        WLGKM(4); MFMA8(0, 0, afA, BP_);                                         \
        /* ph1 (0,jp1) */                                                        \
        if ((u_) + 1 < NT) { WVMC(2); } else { WVMC(0); }                        \
        MFMA8(0, 1, afA, BQ_);                                                   \
        /* ph2 (1,jp1) -- jp1 last use; fetch next jp0 into BQ_ */               \
        WLGKM(0); MFMA8(1, 1, afB, BQ_);                                         \
        if ((u_) + 1 < NT) LD_B4(BQ_, 0, (u_) + 1);                              \
        /* ph3 (1,jp0) -- jp0 last use */                                        \
        MFMA8(1, 0, afB, BP_);                                                   \
        /* boundary */                                                           \
        BAR8();                                                                  \
        if ((u_) + 1 < NT) { WVMC(4); } else { WVMC(0); }                        \
        BAR8();                                                                  \
        if ((u_) + 1 < NT) {                                                     \
            LD_B4(BP_, 1, (u_) + 1);                                             \
            RD_A4(afA, 0, sn_);                                                  \
        }                                                                        \
    } while (0)

    if constexpr (BM == 256) {
        for (int u = 0; u < NT; u += 2) {
            TILE256(u, R0, R1);
            if (u + 1 < NT) TILE256(u + 1, R1, R0);
        }
    } else {
        for (int u = 0; u < NT; u += 2) {
            TILE128(u, R0, R1);
            if (u + 1 < NT) TILE128(u + 1, R1, R0);
        }
    }
    WLGKM(0);                          // quiesce before frag-reg reuse

    const int isbf = (MODE == 0 || MODE == 3 || MODE == 4 || MODE == 5) ? *flagp : 1;
    #pragma unroll
    for (int mi = 0; mi < MI; ++mi) {
        #pragma unroll
        for (int j = 0; j < 4; ++j) {
            #pragma unroll
            for (int r = 0; r < 4; ++r) {
                const int row = m0 + wm * (BM / 2) + mi * 16 + quad * 4 + r;
                const int col = n0 + wn * 64 + j * 16 + l16;
                const long idx = (long)bz * cBatch + (long)row * ldc + col;
                float v = acc[mi][j][r];
                if (MODE == 1) {
                    reinterpret_cast<u16*>(Cv)[idx] = f2bf(v * scale);
                } else if (MODE == 2) {
                    reinterpret_cast<u16*>(Cv)[idx] = f2bf(v);
                } else {
                    v += loadIn(bias, col, isbf);
                    if (MODE == 4) v = gelu_fast(v);
                    if (MODE == 3) v += loadIn(res, (long)row * ldc + col, isbf);
                    if (MODE == 5) v += bf2f(((const u16*)res)[(long)row * ldc + col]);
                    if (MODE == 5 && !isbf)
                        reinterpret_cast<float*>(Cv)[idx] = v;
                    else
                        reinterpret_cast<u16*>(Cv)[idx] = f2bf(v);
                }
            }
        }
    }
#undef STAGE_A
#undef STAGE_ALL
#undef BAR8
#undef WVMC
#undef WLGKM
#undef RD_A4
#undef LD_B4
#undef MFMA8
#undef TILE256
#undef TILE128
}

// ---------------- causal softmax: bf16 scores -> bf16 probs ----------------
// Row r: valid cols <= t=r&2047. PV tiles (BM=128, Keff = m0+128 clamp) read
// cols < (t|127)+1 <= (t|255)+1, so zeros are stored out to t|255.
__global__ void softmax_causal(const u16* __restrict__ S, u16* __restrict__ P) {
    const long row = blockIdx.x;
    const int t = (int)(row & 2047);
    const u16* sr = S + row * 2048;
    u16* pr = P + row * 2048;
    const int tid = threadIdx.x;
    const int s0 = tid * 8;
    float v[8];
    float mx = -INFINITY;
    if (s0 <= t) {
        u16x8 raw = *reinterpret_cast<const u16x8*>(sr + s0);
        #pragma unroll
        for (int i = 0; i < 8; i++) {
            float x = bf2f(raw[i]);
            v[i] = (s0 + i <= t) ? x : -INFINITY;
            mx = fmaxf(mx, v[i]);
        }
    } else {
        #pragma unroll
        for (int i = 0; i < 8; i++) v[i] = -INFINITY;
    }
    mx = blockReduce<true>(mx);
    float sum = 0.f;
    #pragma unroll
    for (int i = 0; i < 8; i++) {
        float e = (v[i] == -INFINITY) ? 0.0f : __expf(v[i] - mx);
        v[i] = e;
        sum += e;
    }
    sum = blockReduce<false>(sum);
    float inv = 1.0f / sum;
    if (s0 <= (t | 255)) {
        u16x8 o;
        #pragma unroll
        for (int i = 0; i < 8; i++) o[i] = f2bf(v[i] * inv);
        *reinterpret_cast<u16x8*>(pr + s0) = o;
    }
}

// ---------------------------------------------------------------------------
extern "C" void kernel_launch(void* const* d_in, const int* in_sizes, int n_in,
                              void* d_out, int out_size, void* d_ws, size_t ws_size,
                              hipStream_t stream) {
    const void* x      = d_in[0];
    const void* w_attn = d_in[1];
    const void* b_attn = d_in[2];
    const void* w_proj = d_in[3];
    const void* b_proj = d_in[4];
    const void* ln1_g  = d_in[5];
    const void* ln1_b  = d_in[6];
    const void* ln2_g  = d_in[7];
    const void* ln2_b  = d_in[8];
    const void* w_fc   = d_in[9];
    const void* b_fc   = d_in[10];
    const void* w_fc2  = d_in[11];
    const void* b_fc2  = d_in[12];

    // workspace layout (176.16 MB + flag)
    char* ws = (char*)d_ws;
    u16*   hbuf   = (u16*)(ws);                      // 16.78 MB: h -> y -> h2
    u16*   qkv    = (u16*)(ws + 16777216);           // 50.33 MB (later: probs+x1)
    u16*   S      = (u16*)(ws + 67108864);           // 64 MB scores (later: g1)
    u16*   wattnT = (u16*)(ws + 134217728);          // 25.17 MB of w^T
    u16*   wprojT = wattnT + 3072 * 1024;
    u16*   wfcT   = wprojT + 1024 * 1024;
    u16*   wfc2T  = wfcT + 4096 * 1024;
    u16*   vT     = wfc2T + 1024 * 4096;             // 16.78 MB
    int*   flag   = (int*)(ws + 176160768);
    u16*   probs  = qkv;                   // reuses qkv region after scores
    u16*   x1     = qkv + 16777216;

    detect_dtype<<<1, 256, 0, stream>>>((const u16*)x, flag);

    // weight transposes (raw dtype -> bf16)
    transpose_to_bf16<<<dim3(96, 32, 1),  256, 0, stream>>>(w_attn, 3072, 0, wattnT, 1024, 0, flag);
    transpose_to_bf16<<<dim3(32, 32, 1),  256, 0, stream>>>(w_proj, 1024, 0, wprojT, 1024, 0, flag);
    transpose_to_bf16<<<dim3(128, 32, 1), 256, 0, stream>>>(w_fc,   4096, 0, wfcT,   1024, 0, flag);
    transpose_to_bf16<<<dim3(32, 128, 1), 256, 0, stream>>>(w_fc2,  1024, 0, wfc2T,  4096, 0, flag);

    // h = LN1(x)
    ln_kernel<true><<<8192, 256, 0, stream>>>(x, ln1_g, ln1_b, hbuf, flag);

    // qkv = h @ w_attn + b_attn       [8192, 3072]   BM=256
    gemm_8ph<0, 0, 256><<<dim3(12, 32, 1), 512, 0, stream>>>(
        hbuf, 1024, 0, wattnT, 1024, 0, b_attn, qkv, 3072, 0, nullptr, 0.f, flag, 1024);

    // vT[b] = V[b]^T                   [1024, 2048] x4
    transpose_to_bf16<<<dim3(32, 64, 4), 256, 0, stream>>>(
        qkv + 2048, 3072, (long)2048 * 3072, vT, 2048, (long)1024 * 2048, nullptr);

    // S[b] = 0.125 * q[b] @ k[b]^T    lower-tri 256^2 tiles (36 per batch)
    gemm_8ph<1, 1, 256><<<dim3(36, 1, 4), 512, 0, stream>>>(
        qkv, 3072, (long)2048 * 3072, qkv + 1024, 3072, (long)2048 * 3072,
        nullptr, S, 2048, (long)2048 * 2048, nullptr, 0.125f, flag, 1024);

    // probs = causal softmax(S)  (stores zeros out to t|255)
    softmax_causal<<<8192, 256, 0, stream>>>(S, probs);

    // y[b] = P[b] @ V[b]              [2048, 1024] x4, BM=128, K clamp m0+128
    gemm_8ph<2, 2, 128><<<dim3(4, 16, 4), 512, 0, stream>>>(
        probs, 2048, (long)2048 * 2048, vT, 2048, (long)1024 * 2048,
        nullptr, hbuf, 1024, (long)2048 * 1024, nullptr, 0.f, flag, 2048);

    // x1 = x + y @ w_proj + b_proj    (bf16, in ws)   BM=128, 256 blocks
    gemm_8ph<3, 0, 128><<<dim3(4, 64, 1), 512, 0, stream>>>(
        hbuf, 1024, 0, wprojT, 1024, 0, b_proj, x1, 1024, 0, x, 0.f, flag, 1024);

    // h2 = LN2(x1) -> hbuf
    ln_kernel<false><<<8192, 256, 0, stream>>>(x1, ln2_g, ln2_b, hbuf, flag);

    // g1 = gelu(h2 @ w_fc + b_fc)     [8192, 4096] bf16 in S region   BM=256
    gemm_8ph<4, 0, 256><<<dim3(16, 32, 1), 512, 0, stream>>>(
        hbuf, 1024, 0, wfcT, 1024, 0, b_fc, S, 4096, 0, nullptr, 0.f, flag, 1024);

    // out = x1 + g1 @ w_fc2 + b_fc2   (detected dtype)   BM=128, 256 blocks
    gemm_8ph<5, 0, 128><<<dim3(4, 64, 1), 512, 0, stream>>>(
        S, 4096, 0, wfc2T, 4096, 0, b_fc2, d_out, 1024, 0, x1, 0.f, flag, 4096);
}

// Round 8
// 581.594 us; speedup vs baseline: 1.2494x; 1.2494x over previous
//
#include <hip/hip_runtime.h>
#include <math.h>

// ---------------------------------------------------------------------------
// GPT transformer block, internal bf16 compute / fp32 accumulate.
// B=4, T=2048, D=1024 (8192 rows), 3D=3072, 4D=4096.
// Round 14 (= r13 resubmit; r13 bench was an infra failure, not a kernel
// failure). REVERT r12's B-in-reg experiment (uncoalesced 16-rows-per-instr
// B loads tanked L2 efficiency: 577 -> 727 µs). Back to r11's proven
// A+B-in-LDS barrier-free-interior kernel. On top of r11:
//   - qkv BM=256 (384 blocks = 1.5 rounds, half-empty 2nd round) -> BM=128
//     (768 blocks = 3.0 exact rounds).
//   - fc  BM=256 (512 blocks) -> BM=128 (1024 blocks = 4.0 exact rounds);
//     r11 showed BM=128 per-FLOP >= BM=256 (fc2/proj/pv) with 96 KiB LDS.
// Ledger (r11): per-tile cost scales ~proportionally with tile FLOPs; wins
// come from CU coverage and exact round packing, not schedule micro-tuning.
// ---------------------------------------------------------------------------

typedef unsigned short u16;
typedef __attribute__((ext_vector_type(8))) short bf16x8;   // 8 bf16 = 4 VGPRs
typedef __attribute__((ext_vector_type(8))) unsigned short u16x8;
typedef __attribute__((ext_vector_type(4))) float f32x4;

#define DEV __device__ __forceinline__

#define GLOAD_LDS16(gp, lp)                                                     \
    __builtin_amdgcn_global_load_lds(                                           \
        (const __attribute__((address_space(1))) void*)(gp),                    \
        (__attribute__((address_space(3))) void*)(lp), 16, 0, 0)

// inline-asm LDS b128 read: invisible to SIInsertWaitcnts; pair with explicit
// counted s_waitcnt lgkmcnt + sched_barrier(0) before use (rule #18).
#define DSR128(dst_, p_)                                                        \
    asm volatile("ds_read_b128 %0, %1"                                          \
                 : "=v"(dst_)                                                   \
                 : "v"((unsigned)(unsigned long long)                           \
                       (__attribute__((address_space(3))) const void*)(p_)))

DEV float bf2f(u16 h) {
    union { unsigned u; float f; } t; t.u = ((unsigned)h) << 16; return t.f;
}
DEV u16 f2bf(float f) {
    union { unsigned u; float f; } t; t.f = f;
    unsigned u = t.u;
    return (u16)((u + 0x7FFFu + ((u >> 16) & 1u)) >> 16);   // round-nearest-even
}
DEV float loadIn(const void* p, long i, int isbf) {
    return isbf ? bf2f(((const u16*)p)[i]) : ((const float*)p)[i];
}
// gelu(x) = 0.5x(1+tanh(u)) = x * sigmoid(2u)
DEV float gelu_fast(float x) {
    float u = 1.5957691216057308f * (x + 0.044715f * x * x * x);  // 2*sqrt(2/pi)
    return x * __builtin_amdgcn_rcpf(1.0f + __expf(-u));
}

DEV float waveSum(float v) {
    #pragma unroll
    for (int o = 32; o > 0; o >>= 1) v += __shfl_down(v, o, 64);
    return v;
}
DEV float waveMax(float v) {
    #pragma unroll
    for (int o = 32; o > 0; o >>= 1) v = fmaxf(v, __shfl_down(v, o, 64));
    return v;
}

template <bool IS_MAX>
DEV float blockReduce(float v) {
    __shared__ float tmp[5];
    __syncthreads();
    v = IS_MAX ? waveMax(v) : waveSum(v);
    int lane = threadIdx.x & 63, w = threadIdx.x >> 6;
    if (lane == 0) tmp[w] = v;
    __syncthreads();
    if (threadIdx.x == 0) {
        float r = tmp[0];
        for (int i = 1; i < 4; i++) r = IS_MAX ? fmaxf(r, tmp[i]) : (r + tmp[i]);
        tmp[4] = r;
    }
    __syncthreads();
    return tmp[4];
}

// ---------------- dtype detection (1 block) --------------------------------
__global__ void detect_dtype(const u16* __restrict__ xr, int* __restrict__ flag) {
    const int tid = threadIdx.x;           // 256
    int cnt = 0;
    #pragma unroll
    for (int i = 0; i < 16; i++) {
        unsigned u = xr[2 * (tid + 256 * i)];      // even u16 indices
        unsigned e = (u >> 7) & 0xFF;              // bf16 exponent field
        cnt += (e >= 100 && e <= 140) ? 1 : 0;     // ~always for bf16 N(0,1)
    }
    __shared__ int sh[4];
    #pragma unroll
    for (int o = 32; o > 0; o >>= 1) cnt += __shfl_down(cnt, o, 64);
    if ((tid & 63) == 0) sh[tid >> 6] = cnt;
    __syncthreads();
    if (tid == 0) flag[0] = (sh[0] + sh[1] + sh[2] + sh[3] > 2048) ? 1 : 0;
}

// ---------------- LayerNorm (D=1024, one 256-thread block per row) ---------
template <bool RAW_IN>
__global__ void ln_kernel(const void* __restrict__ x, const void* __restrict__ g,
                          const void* __restrict__ b, u16* __restrict__ out,
                          const int* __restrict__ flagp) {
    const int isbf = *flagp;
    const int inbf = RAW_IN ? isbf : 1;
    const long base = (long)blockIdx.x * 1024;
    const int tid = threadIdx.x;
    float v[4];
    #pragma unroll
    for (int j = 0; j < 4; j++) v[j] = loadIn(x, base + tid + 256 * j, inbf);
    float mu = blockReduce<false>(v[0] + v[1] + v[2] + v[3]) * (1.0f / 1024.0f);
    float d[4], sq = 0.f;
    #pragma unroll
    for (int j = 0; j < 4; j++) { d[j] = v[j] - mu; sq += d[j] * d[j]; }
    float var = blockReduce<false>(sq) * (1.0f / 1024.0f);
    float rstd = rsqrtf(var + 1e-5f);
    #pragma unroll
    for (int j = 0; j < 4; j++) {
        int c = tid + 256 * j;
        out[base + c] = f2bf(d[j] * rstd * loadIn(g, c, isbf) + loadIn(b, c, isbf));
    }
}

// ---------------- 32x32 transpose -> bf16 ----------------------------------
__global__ void transpose_to_bf16(const void* __restrict__ in, int ldin, long inBatch,
                                  u16* __restrict__ out, int ldout, long outBatch,
                                  const int* __restrict__ flagp) {
    __shared__ u16 tile[32][33];
    const int isbf = flagp ? *flagp : 1;
    const long ibase = (long)blockIdx.z * inBatch;
    out += (long)blockIdx.z * outBatch;
    const int bc = blockIdx.x * 32, br = blockIdx.y * 32;
    const int tx = threadIdx.x & 31, ty = threadIdx.x >> 5;   // 256 thr
    #pragma unroll
    for (int i = 0; i < 32; i += 8)
        tile[ty + i][tx] = f2bf(loadIn(in, ibase + (long)(br + ty + i) * ldin + bc + tx, isbf));
    __syncthreads();
    #pragma unroll
    for (int i = 0; i < 32; i += 8)
        out[(long)(bc + ty + i) * ldout + br + tx] = tile[tx][ty + i];
}

// ---------------- BMx256 barrier-free-interior GEMM ------------------------
// C[M,N] = A[M,K] @ (Bt[N,K])^T (+epilogue). M%BM==0, N%256==0, K%64==0.
// 512 threads = 8 waves (2M x 4N), per-wave C tile (BM/2)x64.
// LDS: 2 K-tile slots x (A BMx64 + B 256x64) bf16 (128 or 96 KiB).
// Swizzle: 16B granule g of row r stored at g^(r&7); LDS dest linear,
// global source column pre-swizzled (global_load_lds stays direct).
// Per K-tile u: stage ALL of tile u+1 -> slot sn at tile top; barrier-free
// snake micro-phases (8 MFMA each) with frag reads one phase ahead under
// counted lgkm; boundary barrier+vmcnt(0)+barrier; prefetch next A-q0+bJ0.
// MODE: 0 qkv +bias->bf16   1 scores *scale->bf16   2 pv plain->bf16
//       3 proj +bias+res(raw)->bf16   4 fc +bias,gelu->bf16
//       5 fc2 +bias+res(bf16)->flag dtype
// CAUSAL: 0 none (T1 XCD swizzle), 1 triangular tile enum (BM=256 only),
//         2 K clamp to m0+BM (pv)
template <int MODE, int CAUSAL, int BM>
__global__ __launch_bounds__(512, 2) void gemm_8ph(
        const u16* __restrict__ A, int lda, long aBatch,
        const u16* __restrict__ Bt, int ldb, long bBatch,
        const void* __restrict__ bias,
        void* __restrict__ Cv, int ldc, long cBatch,
        const void* __restrict__ res,
        float scale, const int* __restrict__ flagp, int K) {
    constexpr int AQ = BM / 64;                     // A stage chunks / quads
    constexpr int MI = BM / 32;                     // acc M frags per wave
    __shared__ __align__(16) u16 sA[2][BM * 64];
    __shared__ __align__(16) u16 sB[2][256 * 64];

    int m0, n0;
    if (CAUSAL == 1) {
        // enumerate lower-triangular 256^2 tiles: bx -> (ti, tj), tj <= ti
        const int bx = blockIdx.x;
        int ti = (int)((sqrtf(8.0f * bx + 1.0f) - 1.0f) * 0.5f);
        while ((ti + 1) * (ti + 2) / 2 <= bx) ++ti;
        while (ti * (ti + 1) / 2 > bx) --ti;
        m0 = ti * 256;
        n0 = (bx - ti * (ti + 1) / 2) * 256;
    } else if (CAUSAL == 2) {
        m0 = (gridDim.y - 1 - blockIdx.y) * BM;    // big-NT blocks dispatch first
        n0 = blockIdx.x * 256;
    } else {
        // T1: bijective XCD chunk swizzle (launches have nwg % 8 == 0)
        const int gx  = gridDim.x;
        const int nwg = gx * gridDim.y;
        const int fid = blockIdx.y * gx + blockIdx.x;
        const int swz = (fid & 7) * (nwg >> 3) + (fid >> 3);
        m0 = (swz / gx) * BM;
        n0 = (swz % gx) * 256;
    }
    const int bz = blockIdx.z;
    A  += (long)bz * aBatch;
    Bt += (long)bz * bBatch;

    const int tid  = threadIdx.x;
    const int lane = tid & 63, wv = tid >> 6;
    const int wm = wv >> 2, wn = wv & 3;            // 2 x 4 wave grid
    const int l16 = lane & 15, quad = lane >> 4;
    const int xg = l16 & 7;                         // read-side granule XOR

    // staging mapping: 512 threads cover 64 rows x 8 granules, linear dest
    const int rq   = tid >> 3;                      // 0..63
    const int gsrc = ((tid & 7) ^ (rq & 7)) * 8;    // pre-swizzled source col
    const int gdst = (tid & 7) * 8;                 // linear dest granule
    const int rAb  = (rq < 32) ? rq : 96 + rq;      // A rows (BM=256 chunking)

    int NT = K >> 6;
    if (CAUSAL == 2) NT = min(K, m0 + BM) >> 6;     // probs zero past t|255

#define STAGE_A(t_, q_) do {                                                     \
        const int sl_ = (t_) & 1;                                               \
        const int k0_ = (t_) << 6;                                              \
        const int ra_ = (BM == 256) ? (((q_) << 5) + rAb) : (((q_) << 6) + rq); \
        GLOAD_LDS16(A + (long)(m0 + ra_) * lda + k0_ + gsrc,                    \
                    &sA[sl_][ra_ * 64 + gdst]);                                 \
    } while (0)

#define STAGE_B(t_, q_) do {                                                     \
        const int sl_ = (t_) & 1;                                               \
        const int k0_ = (t_) << 6;                                              \
        const int rb_ = ((q_) << 6) + rq;                                       \
        GLOAD_LDS16(Bt + (long)(n0 + rb_) * ldb + k0_ + gsrc,                   \
                    &sB[sl_][rb_ * 64 + gdst]);                                 \
    } while (0)

#define STAGE_ALL(t_) do {                                                       \
        _Pragma("unroll")                                                       \
        for (int q_ = 0; q_ < AQ; ++q_) STAGE_A(t_, q_);                        \
        _Pragma("unroll")                                                       \
        for (int q_ = 0; q_ < 4; ++q_) STAGE_B(t_, q_);                         \
    } while (0)

#define BAR8() asm volatile("s_barrier" ::: "memory")

#define WVMC(n_) do {                                                            \
        asm volatile("s_waitcnt vmcnt(" #n_ ")" ::: "memory");                   \
        __builtin_amdgcn_sched_barrier(0); } while (0)

#define WLGKM(n_) do {                                                           \
        asm volatile("s_waitcnt lgkmcnt(" #n_ ")" ::: "memory");                 \
        __builtin_amdgcn_sched_barrier(0); } while (0)

    // A quadrant reads for quad qn_ (4x b128) into buf_[2][2]
#define RD_A4(buf_, qn_, sl_) do {                                               \
        DSR128(buf_[0][0], &sA[sl_][(wm * (BM / 2) + (2 * (qn_) + 0) * 16 + l16) * 64 \
                                    + (((0 * 4 + quad) ^ xg) * 8)]);             \
        DSR128(buf_[0][1], &sA[sl_][(wm * (BM / 2) + (2 * (qn_) + 0) * 16 + l16) * 64 \
                                    + (((1 * 4 + quad) ^ xg) * 8)]);             \
        DSR128(buf_[1][0], &sA[sl_][(wm * (BM / 2) + (2 * (qn_) + 1) * 16 + l16) * 64 \
                                    + (((0 * 4 + quad) ^ xg) * 8)]);             \
        DSR128(buf_[1][1], &sA[sl_][(wm * (BM / 2) + (2 * (qn_) + 1) * 16 + l16) * 64 \
                                    + (((1 * 4 + quad) ^ xg) * 8)]);             \
    } while (0)

    // B half jp_ (j = 2*jp_, 2*jp_+1): 4x b128 into buf_[2][2]
#define RD_B4(buf_, jp_, sl_) do {                                               \
        DSR128(buf_[0][0], &sB[sl_][(wn * 64 + (2 * (jp_) + 0) * 16 + l16) * 64  \
                                    + (((0 * 4 + quad) ^ xg) * 8)]);             \
        DSR128(buf_[0][1], &sB[sl_][(wn * 64 + (2 * (jp_) + 0) * 16 + l16) * 64  \
                                    + (((1 * 4 + quad) ^ xg) * 8)]);             \
        DSR128(buf_[1][0], &sB[sl_][(wn * 64 + (2 * (jp_) + 1) * 16 + l16) * 64  \
                                    + (((0 * 4 + quad) ^ xg) * 8)]);             \
        DSR128(buf_[1][1], &sB[sl_][(wn * 64 + (2 * (jp_) + 1) * 16 + l16) * 64  \
                                    + (((1 * 4 + quad) ^ xg) * 8)]);             \
    } while (0)

    // 8 MFMA: acc[2*mq_+f][2*jp_+jj] += A_[f][s] * B_[jj][s]
    // s=0 group first (4 independent), then s=1 (dep distance 4). T5 setprio.
#define MFMA8(mq_, jp_, A_, B_) do {                                             \
        __builtin_amdgcn_s_setprio(1);                                          \
        _Pragma("unroll")                                                        \
        for (int f_ = 0; f_ < 2; ++f_)                                           \
            _Pragma("unroll")                                                    \
            for (int jj_ = 0; jj_ < 2; ++jj_)                                    \
                acc[2 * (mq_) + f_][2 * (jp_) + jj_] =                           \
                    __builtin_amdgcn_mfma_f32_16x16x32_bf16(                     \
                        A_[f_][0], B_[jj_][0],                                   \
                        acc[2 * (mq_) + f_][2 * (jp_) + jj_], 0, 0, 0);          \
        _Pragma("unroll")                                                        \
        for (int f_ = 0; f_ < 2; ++f_)                                           \
            _Pragma("unroll")                                                    \
            for (int jj_ = 0; jj_ < 2; ++jj_)                                    \
                acc[2 * (mq_) + f_][2 * (jp_) + jj_] =                           \
                    __builtin_amdgcn_mfma_f32_16x16x32_bf16(                     \
                        A_[f_][1], B_[jj_][1],                                   \
                        acc[2 * (mq_) + f_][2 * (jp_) + jj_], 0, 0, 0);          \
        __builtin_amdgcn_s_setprio(0);                                          \
    } while (0)

    f32x4 acc[MI][4];
    #pragma unroll
    for (int i = 0; i < MI; i++)
        #pragma unroll
        for (int j = 0; j < 4; j++) acc[i][j] = f32x4{0.f, 0.f, 0.f, 0.f};

    bf16x8 afA[2][2], afB[2][2], bJ0[2][2], bJ1[2][2];

    // prologue: stage tile 0 into slot 0; confirm; prefetch A-q0 + B-half0.
    STAGE_ALL(0);
    WVMC(0);
    BAR8();
    RD_A4(afA, 0, 0);
    RD_B4(bJ0, 0, 0);

    for (int u = 0; u < NT; ++u) {
        const int su = u & 1, sn = su ^ 1;
        // tile top: stage ALL of tile u+1 into slot sn (never read this tile)
        if (u + 1 < NT) STAGE_ALL(u + 1);
        if (BM == 256) {
            // 8 micro-phases, snake (mq,jp)
            RD_B4(bJ1, 1, su);
            WLGKM(4); MFMA8(0, 0, afA, bJ0);
            RD_A4(afB, 1, su);
            WLGKM(4); MFMA8(0, 1, afA, bJ1);
            WLGKM(0); MFMA8(1, 1, afB, bJ1);
            RD_A4(afA, 2, su);
            WLGKM(4); MFMA8(1, 0, afB, bJ0);
            WLGKM(0); MFMA8(2, 0, afA, bJ0);
            RD_A4(afB, 3, su);
            WLGKM(4); MFMA8(2, 1, afA, bJ1);
            WLGKM(0); MFMA8(3, 1, afB, bJ1);
            MFMA8(3, 0, afB, bJ0);
        } else {
            // 4 micro-phases, snake (mq,jp) over 2x2
            RD_B4(bJ1, 1, su);
            WLGKM(4); MFMA8(0, 0, afA, bJ0);
            RD_A4(afB, 1, su);
            WLGKM(4); MFMA8(0, 1, afA, bJ1);
            WLGKM(0); MFMA8(1, 1, afB, bJ1);
            MFMA8(1, 0, afB, bJ0);
        }
        // boundary: all waves' reads of sn's old data are done (each wave's
        // lgkm wait preceded its barrier arrival) -> safe to expose staging.
        BAR8();
        WVMC(0);                       // own tile-top stages landed (~free)
        BAR8();                        // everyone's landed
        if (u + 1 < NT) {              // prefetch next tile's first frags
            RD_A4(afA, 0, sn);
            RD_B4(bJ0, 0, sn);
        }
    }
    WLGKM(0);                          // quiesce before frag-reg reuse

    const int isbf = (MODE == 0 || MODE == 3 || MODE == 4 || MODE == 5) ? *flagp : 1;
    #pragma unroll
    for (int mi = 0; mi < MI; ++mi) {
        #pragma unroll
        for (int j = 0; j < 4; ++j) {
            #pragma unroll
            for (int r = 0; r < 4; ++r) {
                const int row = m0 + wm * (BM / 2) + mi * 16 + quad * 4 + r;
                const int col = n0 + wn * 64 + j * 16 + l16;
                const long idx = (long)bz * cBatch + (long)row * ldc + col;
                float v = acc[mi][j][r];
                if (MODE == 1) {
                    reinterpret_cast<u16*>(Cv)[idx] = f2bf(v * scale);
                } else if (MODE == 2) {
                    reinterpret_cast<u16*>(Cv)[idx] = f2bf(v);
                } else {
                    v += loadIn(bias, col, isbf);
                    if (MODE == 4) v = gelu_fast(v);
                    if (MODE == 3) v += loadIn(res, (long)row * ldc + col, isbf);
                    if (MODE == 5) v += bf2f(((const u16*)res)[(long)row * ldc + col]);
                    if (MODE == 5 && !isbf)
                        reinterpret_cast<float*>(Cv)[idx] = v;
                    else
                        reinterpret_cast<u16*>(Cv)[idx] = f2bf(v);
                }
            }
        }
    }
#undef STAGE_A
#undef STAGE_B
#undef STAGE_ALL
#undef BAR8
#undef WVMC
#undef WLGKM
#undef RD_A4
#undef RD_B4
#undef MFMA8
}

// ---------------- causal softmax: bf16 scores -> bf16 probs ----------------
// Row r: valid cols <= t=r&2047. PV tiles (BM=128, Keff = m0+128 clamp) read
// cols < (t|127)+1 <= (t|255)+1, so zeros are stored out to t|255.
__global__ void softmax_causal(const u16* __restrict__ S, u16* __restrict__ P) {
    const long row = blockIdx.x;
    const int t = (int)(row & 2047);
    const u16* sr = S + row * 2048;
    u16* pr = P + row * 2048;
    const int tid = threadIdx.x;
    const int s0 = tid * 8;
    float v[8];
    float mx = -INFINITY;
    if (s0 <= t) {
        u16x8 raw = *reinterpret_cast<const u16x8*>(sr + s0);
        #pragma unroll
        for (int i = 0; i < 8; i++) {
            float x = bf2f(raw[i]);
            v[i] = (s0 + i <= t) ? x : -INFINITY;
            mx = fmaxf(mx, v[i]);
        }
    } else {
        #pragma unroll
        for (int i = 0; i < 8; i++) v[i] = -INFINITY;
    }
    mx = blockReduce<true>(mx);
    float sum = 0.f;
    #pragma unroll
    for (int i = 0; i < 8; i++) {
        float e = (v[i] == -INFINITY) ? 0.0f : __expf(v[i] - mx);
        v[i] = e;
        sum += e;
    }
    sum = blockReduce<false>(sum);
    float inv = 1.0f / sum;
    if (s0 <= (t | 255)) {
        u16x8 o;
        #pragma unroll
        for (int i = 0; i < 8; i++) o[i] = f2bf(v[i] * inv);
        *reinterpret_cast<u16x8*>(pr + s0) = o;
    }
}

// ---------------------------------------------------------------------------
extern "C" void kernel_launch(void* const* d_in, const int* in_sizes, int n_in,
                              void* d_out, int out_size, void* d_ws, size_t ws_size,
                              hipStream_t stream) {
    const void* x      = d_in[0];
    const void* w_attn = d_in[1];
    const void* b_attn = d_in[2];
    const void* w_proj = d_in[3];
    const void* b_proj = d_in[4];
    const void* ln1_g  = d_in[5];
    const void* ln1_b  = d_in[6];
    const void* ln2_g  = d_in[7];
    const void* ln2_b  = d_in[8];
    const void* w_fc   = d_in[9];
    const void* b_fc   = d_in[10];
    const void* w_fc2  = d_in[11];
    const void* b_fc2  = d_in[12];

    // workspace layout (176.16 MB + flag)
    char* ws = (char*)d_ws;
    u16*   hbuf   = (u16*)(ws);                      // 16.78 MB: h -> y -> h2
    u16*   qkv    = (u16*)(ws + 16777216);           // 50.33 MB (later: probs+x1)
    u16*   S      = (u16*)(ws + 67108864);           // 64 MB scores (later: g1)
    u16*   wattnT = (u16*)(ws + 134217728);          // 25.17 MB of w^T
    u16*   wprojT = wattnT + 3072 * 1024;
    u16*   wfcT   = wprojT + 1024 * 1024;
    u16*   wfc2T  = wfcT + 4096 * 1024;
    u16*   vT     = wfc2T + 1024 * 4096;             // 16.78 MB
    int*   flag   = (int*)(ws + 176160768);
    u16*   probs  = qkv;                   // reuses qkv region after scores
    u16*   x1     = qkv + 16777216;

    detect_dtype<<<1, 256, 0, stream>>>((const u16*)x, flag);

    // weight transposes (raw dtype -> bf16)
    transpose_to_bf16<<<dim3(96, 32, 1),  256, 0, stream>>>(w_attn, 3072, 0, wattnT, 1024, 0, flag);
    transpose_to_bf16<<<dim3(32, 32, 1),  256, 0, stream>>>(w_proj, 1024, 0, wprojT, 1024, 0, flag);
    transpose_to_bf16<<<dim3(128, 32, 1), 256, 0, stream>>>(w_fc,   4096, 0, wfcT,   1024, 0, flag);
    transpose_to_bf16<<<dim3(32, 128, 1), 256, 0, stream>>>(w_fc2,  1024, 0, wfc2T,  4096, 0, flag);

    // h = LN1(x)
    ln_kernel<true><<<8192, 256, 0, stream>>>(x, ln1_g, ln1_b, hbuf, flag);

    // qkv = h @ w_attn + b_attn       [8192, 3072]   BM=128, 768 blk = 3 rounds
    gemm_8ph<0, 0, 128><<<dim3(12, 64, 1), 512, 0, stream>>>(
        hbuf, 1024, 0, wattnT, 1024, 0, b_attn, qkv, 3072, 0, nullptr, 0.f, flag, 1024);

    // vT[b] = V[b]^T                   [1024, 2048] x4
    transpose_to_bf16<<<dim3(32, 64, 4), 256, 0, stream>>>(
        qkv + 2048, 3072, (long)2048 * 3072, vT, 2048, (long)1024 * 2048, nullptr);

    // S[b] = 0.125 * q[b] @ k[b]^T    lower-tri 256^2 tiles (36 per batch)
    gemm_8ph<1, 1, 256><<<dim3(36, 1, 4), 512, 0, stream>>>(
        qkv, 3072, (long)2048 * 3072, qkv + 1024, 3072, (long)2048 * 3072,
        nullptr, S, 2048, (long)2048 * 2048, nullptr, 0.125f, flag, 1024);

    // probs = causal softmax(S)  (stores zeros out to t|255)
    softmax_causal<<<8192, 256, 0, stream>>>(S, probs);

    // y[b] = P[b] @ V[b]              [2048, 1024] x4, BM=128, K clamp m0+128
    gemm_8ph<2, 2, 128><<<dim3(4, 16, 4), 512, 0, stream>>>(
        probs, 2048, (long)2048 * 2048, vT, 2048, (long)1024 * 2048,
        nullptr, hbuf, 1024, (long)2048 * 1024, nullptr, 0.f, flag, 2048);

    // x1 = x + y @ w_proj + b_proj    (bf16, in ws)   BM=128, 256 blocks
    gemm_8ph<3, 0, 128><<<dim3(4, 64, 1), 512, 0, stream>>>(
        hbuf, 1024, 0, wprojT, 1024, 0, b_proj, x1, 1024, 0, x, 0.f, flag, 1024);

    // h2 = LN2(x1) -> hbuf
    ln_kernel<false><<<8192, 256, 0, stream>>>(x1, ln2_g, ln2_b, hbuf, flag);

    // g1 = gelu(h2 @ w_fc + b_fc)     [8192, 4096]   BM=128, 1024 blk = 4 rounds
    gemm_8ph<4, 0, 128><<<dim3(16, 64, 1), 512, 0, stream>>>(
        hbuf, 1024, 0, wfcT, 1024, 0, b_fc, S, 4096, 0, nullptr, 0.f, flag, 1024);

    // out = x1 + g1 @ w_fc2 + b_fc2   (detected dtype)   BM=128, 256 blocks
    gemm_8ph<5, 0, 128><<<dim3(4, 64, 1), 512, 0, stream>>>(
        S, 4096, 0, wfc2T, 4096, 0, b_fc2, d_out, 1024, 0, x1, 0.f, flag, 4096);
}

// Round 9
// 574.433 us; speedup vs baseline: 1.2650x; 1.0125x over previous
//
#include <hip/hip_runtime.h>
#include <math.h>

// ---------------------------------------------------------------------------
// GPT transformer block, internal bf16 compute / fp32 accumulate.
// B=4, T=2048, D=1024 (8192 rows), 3D=3072, 4D=4096.
// Round 15: ledger-driven tile packing. Measured per-tile cost: BM=256 tile
// = 8745 cyc, BM=128 = 4845 (prop. to FLOPs) -> tile choice is grid-packing
// + L2 reuse only. Changes vs r14:
//   - fc back to BM=256 (r14's BM=128 doubled FETCH, +12.5 µs).
//   - pv to BM=64 (critical block NT=32: 32x4845=65µs -> 32x~2400=33µs),
//     LDS 80 KiB, launch_bounds(512,4) so 2 blocks/CU can co-reside.
//   - 4 weight transposes fused into one launch (fewer serial gaps).
// qkv stays BM=128 (helped ~8µs in r14); scores stays BM=256 (BM=128 tri
// arithmetic is worse: 2-round makespan).
// ---------------------------------------------------------------------------

typedef unsigned short u16;
typedef __attribute__((ext_vector_type(8))) short bf16x8;   // 8 bf16 = 4 VGPRs
typedef __attribute__((ext_vector_type(8))) unsigned short u16x8;
typedef __attribute__((ext_vector_type(4))) float f32x4;

#define DEV __device__ __forceinline__

#define GLOAD_LDS16(gp, lp)                                                     \
    __builtin_amdgcn_global_load_lds(                                           \
        (const __attribute__((address_space(1))) void*)(gp),                    \
        (__attribute__((address_space(3))) void*)(lp), 16, 0, 0)

// inline-asm LDS b128 read: invisible to SIInsertWaitcnts; pair with explicit
// counted s_waitcnt lgkmcnt + sched_barrier(0) before use (rule #18).
#define DSR128(dst_, p_)                                                        \
    asm volatile("ds_read_b128 %0, %1"                                          \
                 : "=v"(dst_)                                                   \
                 : "v"((unsigned)(unsigned long long)                           \
                       (__attribute__((address_space(3))) const void*)(p_)))

DEV float bf2f(u16 h) {
    union { unsigned u; float f; } t; t.u = ((unsigned)h) << 16; return t.f;
}
DEV u16 f2bf(float f) {
    union { unsigned u; float f; } t; t.f = f;
    unsigned u = t.u;
    return (u16)((u + 0x7FFFu + ((u >> 16) & 1u)) >> 16);   // round-nearest-even
}
DEV float loadIn(const void* p, long i, int isbf) {
    return isbf ? bf2f(((const u16*)p)[i]) : ((const float*)p)[i];
}
// gelu(x) = 0.5x(1+tanh(u)) = x * sigmoid(2u)
DEV float gelu_fast(float x) {
    float u = 1.5957691216057308f * (x + 0.044715f * x * x * x);  // 2*sqrt(2/pi)
    return x * __builtin_amdgcn_rcpf(1.0f + __expf(-u));
}

DEV float waveSum(float v) {
    #pragma unroll
    for (int o = 32; o > 0; o >>= 1) v += __shfl_down(v, o, 64);
    return v;
}
DEV float waveMax(float v) {
    #pragma unroll
    for (int o = 32; o > 0; o >>= 1) v = fmaxf(v, __shfl_down(v, o, 64));
    return v;
}

template <bool IS_MAX>
DEV float blockReduce(float v) {
    __shared__ float tmp[5];
    __syncthreads();
    v = IS_MAX ? waveMax(v) : waveSum(v);
    int lane = threadIdx.x & 63, w = threadIdx.x >> 6;
    if (lane == 0) tmp[w] = v;
    __syncthreads();
    if (threadIdx.x == 0) {
        float r = tmp[0];
        for (int i = 1; i < 4; i++) r = IS_MAX ? fmaxf(r, tmp[i]) : (r + tmp[i]);
        tmp[4] = r;
    }
    __syncthreads();
    return tmp[4];
}

// ---------------- dtype detection (1 block) --------------------------------
__global__ void detect_dtype(const u16* __restrict__ xr, int* __restrict__ flag) {
    const int tid = threadIdx.x;           // 256
    int cnt = 0;
    #pragma unroll
    for (int i = 0; i < 16; i++) {
        unsigned u = xr[2 * (tid + 256 * i)];      // even u16 indices
        unsigned e = (u >> 7) & 0xFF;              // bf16 exponent field
        cnt += (e >= 100 && e <= 140) ? 1 : 0;     // ~always for bf16 N(0,1)
    }
    __shared__ int sh[4];
    #pragma unroll
    for (int o = 32; o > 0; o >>= 1) cnt += __shfl_down(cnt, o, 64);
    if ((tid & 63) == 0) sh[tid >> 6] = cnt;
    __syncthreads();
    if (tid == 0) flag[0] = (sh[0] + sh[1] + sh[2] + sh[3] > 2048) ? 1 : 0;
}

// ---------------- LayerNorm (D=1024, one 256-thread block per row) ---------
template <bool RAW_IN>
__global__ void ln_kernel(const void* __restrict__ x, const void* __restrict__ g,
                          const void* __restrict__ b, u16* __restrict__ out,
                          const int* __restrict__ flagp) {
    const int isbf = *flagp;
    const int inbf = RAW_IN ? isbf : 1;
    const long base = (long)blockIdx.x * 1024;
    const int tid = threadIdx.x;
    float v[4];
    #pragma unroll
    for (int j = 0; j < 4; j++) v[j] = loadIn(x, base + tid + 256 * j, inbf);
    float mu = blockReduce<false>(v[0] + v[1] + v[2] + v[3]) * (1.0f / 1024.0f);
    float d[4], sq = 0.f;
    #pragma unroll
    for (int j = 0; j < 4; j++) { d[j] = v[j] - mu; sq += d[j] * d[j]; }
    float var = blockReduce<false>(sq) * (1.0f / 1024.0f);
    float rstd = rsqrtf(var + 1e-5f);
    #pragma unroll
    for (int j = 0; j < 4; j++) {
        int c = tid + 256 * j;
        out[base + c] = f2bf(d[j] * rstd * loadIn(g, c, isbf) + loadIn(b, c, isbf));
    }
}

// ---------------- 32x32 transpose -> bf16 ----------------------------------
__global__ void transpose_to_bf16(const void* __restrict__ in, int ldin, long inBatch,
                                  u16* __restrict__ out, int ldout, long outBatch,
                                  const int* __restrict__ flagp) {
    __shared__ u16 tile[32][33];
    const int isbf = flagp ? *flagp : 1;
    const long ibase = (long)blockIdx.z * inBatch;
    out += (long)blockIdx.z * outBatch;
    const int bc = blockIdx.x * 32, br = blockIdx.y * 32;
    const int tx = threadIdx.x & 31, ty = threadIdx.x >> 5;   // 256 thr
    #pragma unroll
    for (int i = 0; i < 32; i += 8)
        tile[ty + i][tx] = f2bf(loadIn(in, ibase + (long)(br + ty + i) * ldin + bc + tx, isbf));
    __syncthreads();
    #pragma unroll
    for (int i = 0; i < 32; i += 8)
        out[(long)(bc + ty + i) * ldout + br + tx] = tile[tx][ty + i];
}

// ---------------- fused weight transposes (one launch) ---------------------
// Segments (blocks): w_attn 96x32=3072 | w_proj 32x32=1024 | w_fc 128x32=4096
// | w_fc2 32x128=4096.  Total 12288 blocks.
__global__ void transpose_weights(const void* __restrict__ w_attn,
                                  const void* __restrict__ w_proj,
                                  const void* __restrict__ w_fc,
                                  const void* __restrict__ w_fc2,
                                  u16* __restrict__ wattnT, u16* __restrict__ wprojT,
                                  u16* __restrict__ wfcT, u16* __restrict__ wfc2T,
                                  const int* __restrict__ flagp) {
    __shared__ u16 tile[32][33];
    const int isbf = *flagp;
    int id = blockIdx.x;
    const void* in; u16* out; int ldin, ldout, gx;
    if (id < 3072)      {            in = w_attn; out = wattnT; ldin = 3072; ldout = 1024; gx = 96;  }
    else if (id < 4096) { id -= 3072; in = w_proj; out = wprojT; ldin = 1024; ldout = 1024; gx = 32;  }
    else if (id < 8192) { id -= 4096; in = w_fc;   out = wfcT;   ldin = 4096; ldout = 1024; gx = 128; }
    else                { id -= 8192; in = w_fc2;  out = wfc2T;  ldin = 1024; ldout = 4096; gx = 32;  }
    const int bc = (id % gx) * 32, br = (id / gx) * 32;
    const int tx = threadIdx.x & 31, ty = threadIdx.x >> 5;   // 256 thr
    #pragma unroll
    for (int i = 0; i < 32; i += 8)
        tile[ty + i][tx] = f2bf(loadIn(in, (long)(br + ty + i) * ldin + bc + tx, isbf));
    __syncthreads();
    #pragma unroll
    for (int i = 0; i < 32; i += 8)
        out[(long)(bc + ty + i) * ldout + br + tx] = tile[tx][ty + i];
}

// ---------------- BMx256 barrier-free-interior GEMM ------------------------
// C[M,N] = A[M,K] @ (Bt[N,K])^T (+epilogue). M%BM==0, N%256==0, K%64==0.
// 512 threads = 8 waves (2M x 4N), per-wave C tile (BM/2)x64.
// LDS: 2 K-tile slots x (A BMx64 + B 256x64) bf16 (128 / 96 / 80 KiB).
// Swizzle: 16B granule g of row r stored at g^(r&7); LDS dest linear,
// global source column pre-swizzled (global_load_lds stays direct).
// Per K-tile u: stage ALL of tile u+1 -> slot sn at tile top; barrier-free
// snake micro-phases (8 MFMA each) with frag reads one phase ahead under
// counted lgkm; boundary barrier+vmcnt(0)+barrier; prefetch next A-q0+bJ0.
// MODE: 0 qkv +bias->bf16   1 scores *scale->bf16   2 pv plain->bf16
//       3 proj +bias+res(raw)->bf16   4 fc +bias,gelu->bf16
//       5 fc2 +bias+res(bf16)->flag dtype
// CAUSAL: 0 none (T1 XCD swizzle), 1 triangular tile enum (BM=256 only),
//         2 K clamp to m0+BM (pv)
template <int MODE, int CAUSAL, int BM>
__global__ __launch_bounds__(512, (BM == 64) ? 4 : 2) void gemm_8ph(
        const u16* __restrict__ A, int lda, long aBatch,
        const u16* __restrict__ Bt, int ldb, long bBatch,
        const void* __restrict__ bias,
        void* __restrict__ Cv, int ldc, long cBatch,
        const void* __restrict__ res,
        float scale, const int* __restrict__ flagp, int K) {
    constexpr int AQ = BM / 64 > 0 ? BM / 64 : 1;   // A stage chunks (>=1)
    constexpr int MI = BM / 32;                     // acc M frags per wave
    __shared__ __align__(16) u16 sA[2][BM * 64];
    __shared__ __align__(16) u16 sB[2][256 * 64];

    int m0, n0;
    if (CAUSAL == 1) {
        // enumerate lower-triangular 256^2 tiles: bx -> (ti, tj), tj <= ti
        const int bx = blockIdx.x;
        int ti = (int)((sqrtf(8.0f * bx + 1.0f) - 1.0f) * 0.5f);
        while ((ti + 1) * (ti + 2) / 2 <= bx) ++ti;
        while (ti * (ti + 1) / 2 > bx) --ti;
        m0 = ti * 256;
        n0 = (bx - ti * (ti + 1) / 2) * 256;
    } else if (CAUSAL == 2) {
        m0 = (gridDim.y - 1 - blockIdx.y) * BM;    // big-NT blocks dispatch first
        n0 = blockIdx.x * 256;
    } else {
        // T1: bijective XCD chunk swizzle (launches have nwg % 8 == 0)
        const int gx  = gridDim.x;
        const int nwg = gx * gridDim.y;
        const int fid = blockIdx.y * gx + blockIdx.x;
        const int swz = (fid & 7) * (nwg >> 3) + (fid >> 3);
        m0 = (swz / gx) * BM;
        n0 = (swz % gx) * 256;
    }
    const int bz = blockIdx.z;
    A  += (long)bz * aBatch;
    Bt += (long)bz * bBatch;

    const int tid  = threadIdx.x;
    const int lane = tid & 63, wv = tid >> 6;
    const int wm = wv >> 2, wn = wv & 3;            // 2 x 4 wave grid
    const int l16 = lane & 15, quad = lane >> 4;
    const int xg = l16 & 7;                         // read-side granule XOR

    // staging mapping: 512 threads cover 64 rows x 8 granules, linear dest
    const int rq   = tid >> 3;                      // 0..63
    const int gsrc = ((tid & 7) ^ (rq & 7)) * 8;    // pre-swizzled source col
    const int gdst = (tid & 7) * 8;                 // linear dest granule
    const int rAb  = (rq < 32) ? rq : 96 + rq;      // A rows (BM=256 chunking)

    int NT = K >> 6;
    if (CAUSAL == 2) NT = min(K, m0 + BM) >> 6;     // probs zero past t|255

#define STAGE_A(t_, q_) do {                                                     \
        const int sl_ = (t_) & 1;                                               \
        const int k0_ = (t_) << 6;                                              \
        const int ra_ = (BM == 256) ? (((q_) << 5) + rAb) : (((q_) << 6) + rq); \
        GLOAD_LDS16(A + (long)(m0 + ra_) * lda + k0_ + gsrc,                    \
                    &sA[sl_][ra_ * 64 + gdst]);                                 \
    } while (0)

#define STAGE_B(t_, q_) do {                                                     \
        const int sl_ = (t_) & 1;                                               \
        const int k0_ = (t_) << 6;                                              \
        const int rb_ = ((q_) << 6) + rq;                                       \
        GLOAD_LDS16(Bt + (long)(n0 + rb_) * ldb + k0_ + gsrc,                   \
                    &sB[sl_][rb_ * 64 + gdst]);                                 \
    } while (0)

#define STAGE_ALL(t_) do {                                                       \
        _Pragma("unroll")                                                       \
        for (int q_ = 0; q_ < AQ; ++q_) STAGE_A(t_, q_);                        \
        _Pragma("unroll")                                                       \
        for (int q_ = 0; q_ < 4; ++q_) STAGE_B(t_, q_);                         \
    } while (0)

#define BAR8() asm volatile("s_barrier" ::: "memory")

#define WVMC(n_) do {                                                            \
        asm volatile("s_waitcnt vmcnt(" #n_ ")" ::: "memory");                   \
        __builtin_amdgcn_sched_barrier(0); } while (0)

#define WLGKM(n_) do {                                                           \
        asm volatile("s_waitcnt lgkmcnt(" #n_ ")" ::: "memory");                 \
        __builtin_amdgcn_sched_barrier(0); } while (0)

    // A quadrant reads for quad qn_ (4x b128) into buf_[2][2]
#define RD_A4(buf_, qn_, sl_) do {                                               \
        DSR128(buf_[0][0], &sA[sl_][(wm * (BM / 2) + (2 * (qn_) + 0) * 16 + l16) * 64 \
                                    + (((0 * 4 + quad) ^ xg) * 8)]);             \
        DSR128(buf_[0][1], &sA[sl_][(wm * (BM / 2) + (2 * (qn_) + 0) * 16 + l16) * 64 \
                                    + (((1 * 4 + quad) ^ xg) * 8)]);             \
        DSR128(buf_[1][0], &sA[sl_][(wm * (BM / 2) + (2 * (qn_) + 1) * 16 + l16) * 64 \
                                    + (((0 * 4 + quad) ^ xg) * 8)]);             \
        DSR128(buf_[1][1], &sA[sl_][(wm * (BM / 2) + (2 * (qn_) + 1) * 16 + l16) * 64 \
                                    + (((1 * 4 + quad) ^ xg) * 8)]);             \
    } while (0)

    // B half jp_ (j = 2*jp_, 2*jp_+1): 4x b128 into buf_[2][2]
#define RD_B4(buf_, jp_, sl_) do {                                               \
        DSR128(buf_[0][0], &sB[sl_][(wn * 64 + (2 * (jp_) + 0) * 16 + l16) * 64  \
                                    + (((0 * 4 + quad) ^ xg) * 8)]);             \
        DSR128(buf_[0][1], &sB[sl_][(wn * 64 + (2 * (jp_) + 0) * 16 + l16) * 64  \
                                    + (((1 * 4 + quad) ^ xg) * 8)]);             \
        DSR128(buf_[1][0], &sB[sl_][(wn * 64 + (2 * (jp_) + 1) * 16 + l16) * 64  \
                                    + (((0 * 4 + quad) ^ xg) * 8)]);             \
        DSR128(buf_[1][1], &sB[sl_][(wn * 64 + (2 * (jp_) + 1) * 16 + l16) * 64  \
                                    + (((1 * 4 + quad) ^ xg) * 8)]);             \
    } while (0)

    // 8 MFMA: acc[2*mq_+f][2*jp_+jj] += A_[f][s] * B_[jj][s]
    // s=0 group first (4 independent), then s=1 (dep distance 4). T5 setprio.
#define MFMA8(mq_, jp_, A_, B_) do {                                             \
        __builtin_amdgcn_s_setprio(1);                                          \
        _Pragma("unroll")                                                        \
        for (int f_ = 0; f_ < 2; ++f_)                                           \
            _Pragma("unroll")                                                    \
            for (int jj_ = 0; jj_ < 2; ++jj_)                                    \
                acc[2 * (mq_) + f_][2 * (jp_) + jj_] =                           \
                    __builtin_amdgcn_mfma_f32_16x16x32_bf16(                     \
                        A_[f_][0], B_[jj_][0],                                   \
                        acc[2 * (mq_) + f_][2 * (jp_) + jj_], 0, 0, 0);          \
        _Pragma("unroll")                                                        \
        for (int f_ = 0; f_ < 2; ++f_)                                           \
            _Pragma("unroll")                                                    \
            for (int jj_ = 0; jj_ < 2; ++jj_)                                    \
                acc[2 * (mq_) + f_][2 * (jp_) + jj_] =                           \
                    __builtin_amdgcn_mfma_f32_16x16x32_bf16(                     \
                        A_[f_][1], B_[jj_][1],                                   \
                        acc[2 * (mq_) + f_][2 * (jp_) + jj_], 0, 0, 0);          \
        __builtin_amdgcn_s_setprio(0);                                          \
    } while (0)

    f32x4 acc[MI][4];
    #pragma unroll
    for (int i = 0; i < MI; i++)
        #pragma unroll
        for (int j = 0; j < 4; j++) acc[i][j] = f32x4{0.f, 0.f, 0.f, 0.f};

    bf16x8 afA[2][2], afB[2][2], bJ0[2][2], bJ1[2][2];

    // prologue: stage tile 0 into slot 0; confirm; prefetch A-q0 + B-half0.
    STAGE_ALL(0);
    WVMC(0);
    BAR8();
    RD_A4(afA, 0, 0);
    RD_B4(bJ0, 0, 0);

    for (int u = 0; u < NT; ++u) {
        const int su = u & 1, sn = su ^ 1;
        // tile top: stage ALL of tile u+1 into slot sn (never read this tile)
        if (u + 1 < NT) STAGE_ALL(u + 1);
        if (BM == 256) {
            // 8 micro-phases, snake (mq,jp)
            RD_B4(bJ1, 1, su);
            WLGKM(4); MFMA8(0, 0, afA, bJ0);
            RD_A4(afB, 1, su);
            WLGKM(4); MFMA8(0, 1, afA, bJ1);
            WLGKM(0); MFMA8(1, 1, afB, bJ1);
            RD_A4(afA, 2, su);
            WLGKM(4); MFMA8(1, 0, afB, bJ0);
            WLGKM(0); MFMA8(2, 0, afA, bJ0);
            RD_A4(afB, 3, su);
            WLGKM(4); MFMA8(2, 1, afA, bJ1);
            WLGKM(0); MFMA8(3, 1, afB, bJ1);
            MFMA8(3, 0, afB, bJ0);
        } else if (BM == 128) {
            // 4 micro-phases, snake (mq,jp) over 2x2
            RD_B4(bJ1, 1, su);
            WLGKM(4); MFMA8(0, 0, afA, bJ0);
            RD_A4(afB, 1, su);
            WLGKM(4); MFMA8(0, 1, afA, bJ1);
            WLGKM(0); MFMA8(1, 1, afB, bJ1);
            MFMA8(1, 0, afB, bJ0);
        } else {
            // BM == 64: 2 micro-phases (mq=0 only)
            RD_B4(bJ1, 1, su);
            WLGKM(4); MFMA8(0, 0, afA, bJ0);
            WLGKM(0); MFMA8(0, 1, afA, bJ1);
        }
        // boundary: all waves' reads of sn's old data are done (each wave's
        // lgkm wait preceded its barrier arrival) -> safe to expose staging.
        BAR8();
        WVMC(0);                       // own tile-top stages landed (~free)
        BAR8();                        // everyone's landed
        if (u + 1 < NT) {              // prefetch next tile's first frags
            RD_A4(afA, 0, sn);
            RD_B4(bJ0, 0, sn);
        }
    }
    WLGKM(0);                          // quiesce before frag-reg reuse

    const int isbf = (MODE == 0 || MODE == 3 || MODE == 4 || MODE == 5) ? *flagp : 1;
    #pragma unroll
    for (int mi = 0; mi < MI; ++mi) {
        #pragma unroll
        for (int j = 0; j < 4; ++j) {
            #pragma unroll
            for (int r = 0; r < 4; ++r) {
                const int row = m0 + wm * (BM / 2) + mi * 16 + quad * 4 + r;
                const int col = n0 + wn * 64 + j * 16 + l16;
                const long idx = (long)bz * cBatch + (long)row * ldc + col;
                float v = acc[mi][j][r];
                if (MODE == 1) {
                    reinterpret_cast<u16*>(Cv)[idx] = f2bf(v * scale);
                } else if (MODE == 2) {
                    reinterpret_cast<u16*>(Cv)[idx] = f2bf(v);
                } else {
                    v += loadIn(bias, col, isbf);
                    if (MODE == 4) v = gelu_fast(v);
                    if (MODE == 3) v += loadIn(res, (long)row * ldc + col, isbf);
                    if (MODE == 5) v += bf2f(((const u16*)res)[(long)row * ldc + col]);
                    if (MODE == 5 && !isbf)
                        reinterpret_cast<float*>(Cv)[idx] = v;
                    else
                        reinterpret_cast<u16*>(Cv)[idx] = f2bf(v);
                }
            }
        }
    }
#undef STAGE_A
#undef STAGE_B
#undef STAGE_ALL
#undef BAR8
#undef WVMC
#undef WLGKM
#undef RD_A4
#undef RD_B4
#undef MFMA8
}

// ---------------- causal softmax: bf16 scores -> bf16 probs ----------------
// Row r: valid cols <= t=r&2047. PV tiles (BM=64, Keff = m0+64 clamp) read
// cols < (t|63)+1... stores zeros out to t|255 (covers any BM <= 256 clamp).
__global__ void softmax_causal(const u16* __restrict__ S, u16* __restrict__ P) {
    const long row = blockIdx.x;
    const int t = (int)(row & 2047);
    const u16* sr = S + row * 2048;
    u16* pr = P + row * 2048;
    const int tid = threadIdx.x;
    const int s0 = tid * 8;
    float v[8];
    float mx = -INFINITY;
    if (s0 <= t) {
        u16x8 raw = *reinterpret_cast<const u16x8*>(sr + s0);
        #pragma unroll
        for (int i = 0; i < 8; i++) {
            float x = bf2f(raw[i]);
            v[i] = (s0 + i <= t) ? x : -INFINITY;
            mx = fmaxf(mx, v[i]);
        }
    } else {
        #pragma unroll
        for (int i = 0; i < 8; i++) v[i] = -INFINITY;
    }
    mx = blockReduce<true>(mx);
    float sum = 0.f;
    #pragma unroll
    for (int i = 0; i < 8; i++) {
        float e = (v[i] == -INFINITY) ? 0.0f : __expf(v[i] - mx);
        v[i] = e;
        sum += e;
    }
    sum = blockReduce<false>(sum);
    float inv = 1.0f / sum;
    if (s0 <= (t | 255)) {
        u16x8 o;
        #pragma unroll
        for (int i = 0; i < 8; i++) o[i] = f2bf(v[i] * inv);
        *reinterpret_cast<u16x8*>(pr + s0) = o;
    }
}

// ---------------------------------------------------------------------------
extern "C" void kernel_launch(void* const* d_in, const int* in_sizes, int n_in,
                              void* d_out, int out_size, void* d_ws, size_t ws_size,
                              hipStream_t stream) {
    const void* x      = d_in[0];
    const void* w_attn = d_in[1];
    const void* b_attn = d_in[2];
    const void* w_proj = d_in[3];
    const void* b_proj = d_in[4];
    const void* ln1_g  = d_in[5];
    const void* ln1_b  = d_in[6];
    const void* ln2_g  = d_in[7];
    const void* ln2_b  = d_in[8];
    const void* w_fc   = d_in[9];
    const void* b_fc   = d_in[10];
    const void* w_fc2  = d_in[11];
    const void* b_fc2  = d_in[12];

    // workspace layout (176.16 MB + flag)
    char* ws = (char*)d_ws;
    u16*   hbuf   = (u16*)(ws);                      // 16.78 MB: h -> y -> h2
    u16*   qkv    = (u16*)(ws + 16777216);           // 50.33 MB (later: probs+x1)
    u16*   S      = (u16*)(ws + 67108864);           // 64 MB scores (later: g1)
    u16*   wattnT = (u16*)(ws + 134217728);          // 25.17 MB of w^T
    u16*   wprojT = wattnT + 3072 * 1024;
    u16*   wfcT   = wprojT + 1024 * 1024;
    u16*   wfc2T  = wfcT + 4096 * 1024;
    u16*   vT     = wfc2T + 1024 * 4096;             // 16.78 MB
    int*   flag   = (int*)(ws + 176160768);
    u16*   probs  = qkv;                   // reuses qkv region after scores
    u16*   x1     = qkv + 16777216;

    detect_dtype<<<1, 256, 0, stream>>>((const u16*)x, flag);

    // all 4 weight transposes in one launch (raw dtype -> bf16)
    transpose_weights<<<12288, 256, 0, stream>>>(
        w_attn, w_proj, w_fc, w_fc2, wattnT, wprojT, wfcT, wfc2T, flag);

    // h = LN1(x)
    ln_kernel<true><<<8192, 256, 0, stream>>>(x, ln1_g, ln1_b, hbuf, flag);

    // qkv = h @ w_attn + b_attn       [8192, 3072]   BM=128, 768 blk = 3 rounds
    gemm_8ph<0, 0, 128><<<dim3(12, 64, 1), 512, 0, stream>>>(
        hbuf, 1024, 0, wattnT, 1024, 0, b_attn, qkv, 3072, 0, nullptr, 0.f, flag, 1024);

    // vT[b] = V[b]^T                   [1024, 2048] x4
    transpose_to_bf16<<<dim3(32, 64, 4), 256, 0, stream>>>(
        qkv + 2048, 3072, (long)2048 * 3072, vT, 2048, (long)1024 * 2048, nullptr);

    // S[b] = 0.125 * q[b] @ k[b]^T    lower-tri 256^2 tiles (36 per batch)
    gemm_8ph<1, 1, 256><<<dim3(36, 1, 4), 512, 0, stream>>>(
        qkv, 3072, (long)2048 * 3072, qkv + 1024, 3072, (long)2048 * 3072,
        nullptr, S, 2048, (long)2048 * 2048, nullptr, 0.125f, flag, 1024);

    // probs = causal softmax(S)  (stores zeros out to t|255)
    softmax_causal<<<8192, 256, 0, stream>>>(S, probs);

    // y[b] = P[b] @ V[b]              [2048, 1024] x4, BM=64, K clamp m0+64
    gemm_8ph<2, 2, 64><<<dim3(4, 32, 4), 512, 0, stream>>>(
        probs, 2048, (long)2048 * 2048, vT, 2048, (long)1024 * 2048,
        nullptr, hbuf, 1024, (long)2048 * 1024, nullptr, 0.f, flag, 2048);

    // x1 = x + y @ w_proj + b_proj    (bf16, in ws)   BM=128, 256 blocks
    gemm_8ph<3, 0, 128><<<dim3(4, 64, 1), 512, 0, stream>>>(
        hbuf, 1024, 0, wprojT, 1024, 0, b_proj, x1, 1024, 0, x, 0.f, flag, 1024);

    // h2 = LN2(x1) -> hbuf
    ln_kernel<false><<<8192, 256, 0, stream>>>(x1, ln2_g, ln2_b, hbuf, flag);

    // g1 = gelu(h2 @ w_fc + b_fc)     [8192, 4096]   BM=256, 512 blk = 2 rounds
    gemm_8ph<4, 0, 256><<<dim3(16, 32, 1), 512, 0, stream>>>(
        hbuf, 1024, 0, wfcT, 1024, 0, b_fc, S, 4096, 0, nullptr, 0.f, flag, 1024);

    // out = x1 + g1 @ w_fc2 + b_fc2   (detected dtype)   BM=128, 256 blocks
    gemm_8ph<5, 0, 128><<<dim3(4, 64, 1), 512, 0, stream>>>(
        S, 4096, 0, wfc2T, 4096, 0, b_fc2, d_out, 1024, 0, x1, 0.f, flag, 4096);
}